// Round 6
// baseline (316.718 us; speedup 1.0000x reference)
//
#include <hip/hip_runtime.h>
#include <math.h>

#define NN 10000
#define NE 100000
#define CC 6
#define LL 6
#define BB 16
#define FUNC_LO 100
#define FUNC_HI 9900
#define EPSF 1e-5f
#define NSLOT 64

struct Slot { double s1, s2; double pad[6]; };  // 64B-padded

struct Params {
  const float *x, *w1v, *b1, *w2v, *b2, *w3v, *b3, *gamma, *beta;
  const int *src, *dst, *w3r, *w3c;
  float *out;
  int *row_start, *counts, *fill, *csr;      // dst -> incoming edges
  int *row2, *counts2, *fill2, *csr2;        // func node -> outgoing selected-edge rows (k)
  float *xT, *h, *z3a, *z3b;
  Slot *part, *baseS;
  int F, Ksel;
};

__device__ __forceinline__ float eluf(float x){ return x > 0.0f ? x : expm1f(x); }

__device__ void block_add_slot(double a, double q, Slot* sl){
  __shared__ double sb1[4], sb2[4];
  #pragma unroll
  for(int off=32;off;off>>=1){ a+=__shfl_down(a,off); q+=__shfl_down(q,off); }
  int wid = threadIdx.x>>6;
  if((threadIdx.x&63)==0){ sb1[wid]=a; sb2[wid]=q; }
  __syncthreads();
  if(threadIdx.x==0){
    double A=sb1[0]+sb1[1]+sb1[2]+sb1[3];
    double Q=sb2[0]+sb2[1]+sb2[2]+sb2[3];
    if(A!=0.0) atomicAdd(&sl->s1,A);
    if(Q!=0.0) atomicAdd(&sl->s2,Q);
  }
  __syncthreads();
}

__device__ void bn_params(const Slot* part, const Slot* baseS, float* m, float* inv){
  __shared__ double s_mv[2];
  if(threadIdx.x < NSLOT){
    double a = part[threadIdx.x].s1 + baseS[threadIdx.x].s1;
    double q = part[threadIdx.x].s2 + baseS[threadIdx.x].s2;
    #pragma unroll
    for(int off=32;off;off>>=1){ a+=__shfl_down(a,off); q+=__shfl_down(q,off); }
    if(threadIdx.x==0){
      const double cnt = (double)NE*(double)BB;
      double md = a/cnt, vd = q/cnt - md*md;
      s_mv[0]=md; s_mv[1]=1.0/sqrt(vd+(double)EPSF);
    }
  }
  __syncthreads();
  *m=(float)s_mv[0]; *inv=(float)s_mv[1];
  __syncthreads();
}

// P1: transpose x -> xT; dst histogram; src-selected histogram; base BN sums
// (non-func-src edges keep z3 = b3[e] every layer -> constant contribution).
__global__ __launch_bounds__(256) void kw_P1(Params p){
  int tid = blockIdx.x*256 + threadIdx.x, nt = gridDim.x*256;
  for(int i=tid;i<NN*BB;i+=nt){ int n=i>>4, b=i&15; p.xT[i]=p.x[b*NN+n]; }
  double a=0.0,q=0.0;
  for(int e=tid;e<NE;e+=nt){
    atomicAdd(&p.counts[p.dst[e]],1);
    int s=p.src[e];
    if(!(s>=FUNC_LO && s<FUNC_HI)){ double v=(double)p.b3[e]; a+=v; q+=v*v; }
  }
  for(int k=tid;k<p.Ksel;k+=nt){
    int s=p.w3r[k*CC]/CC;
    atomicAdd(&p.counts2[s-FUNC_LO],1);
  }
  block_add_slot(a*BB, q*BB, &p.baseS[blockIdx.x&(NSLOT-1)]);
}

// Two independent single-block scans: block 0 -> dst-CSR, block 1 -> src-CSR.
__global__ __launch_bounds__(256) void kw_scan(Params p){
  __shared__ int s_scan[256];
  const int*  cin  = (blockIdx.x==0)? p.counts : p.counts2;
  int*        rout = (blockIdx.x==0)? p.row_start : p.row2;
  const int   nel  = (blockIdx.x==0)? NN : p.F;
  const int   CH   = (nel+255)/256;
  int t=threadIdx.x, base=t*CH, s=0;
  for(int k=0;k<CH;k++){ int i=base+k; if(i<nel) s+=cin[i]; }
  s_scan[t]=s; __syncthreads();
  for(int off=1;off<256;off<<=1){
    int v=(t>=off)?s_scan[t-off]:0; __syncthreads();
    s_scan[t]+=v; __syncthreads();
  }
  int run=s_scan[t]-s;
  for(int k=0;k<CH;k++){ int i=base+k; if(i<nel){ rout[i]=run; run+=cin[i]; } }
  if(t==255) rout[nel]=s_scan[255];
}

// Fill both CSRs.
__global__ __launch_bounds__(256) void kw_fill(Params p){
  int tid = blockIdx.x*256 + threadIdx.x, nt = gridDim.x*256;
  for(int e=tid;e<NE;e+=nt){
    int n=p.dst[e];
    int pos=p.row_start[n]+atomicAdd(&p.fill[n],1);
    p.csr[pos]=e;
  }
  for(int k=tid;k<p.Ksel;k+=nt){
    int fi=p.w3r[k*CC]/CC - FUNC_LO;
    int pos=p.row2[fi]+atomicAdd(&p.fill2[fi],1);
    p.csr2[pos]=k;
  }
}

// AB_l (fused): per func node fi (16-lane group, lane=batch):
//  1. BN_{l-1}+residual applied in place to h on incoming edges during the
//     CSR gather; z1 = gather*W1+b1; ELU; z2 = z1*W2+b2; ELU (registers).
//  2. Scatter z3 to outgoing selected edges via src-CSR (each edge has one
//     func src -> no atomics); accumulate BN partial sums.
//  Out-dst edges (dst in output nodes) get the BN+residual in an extra range.
//  z3 ping-pongs (z3p = layer l-1, z3c = layer l) to avoid RAW within the kernel.
__global__ __launch_bounds__(256) void kw_AB(Params p, int l,
    const float* __restrict__ z3p, float* __restrict__ z3c){
  int tid = blockIdx.x*256 + threadIdx.x, nt = gridDim.x*256;
  float m=0.f, inv=0.f, g=0.f, be=0.f;
  if(l>0){
    bn_params(p.part+(l-1)*NSLOT, p.baseS, &m, &inv);
    g=p.gamma[l-1]; be=p.beta[l-1];
  }
  const int FB = p.F*BB;
  const int outBeg = p.row_start[FUNC_HI];
  const int nOutE  = p.row_start[NN] - outBeg;
  const int totalA = FB + ((l>0)? nOutE*BB : 0);
  double a=0.0, q=0.0;
  for(int t=tid;t<totalA;t+=nt){
    if(t<FB){
      int fi=t>>4, b=t&15;
      int n=FUNC_LO+fi;
      float acc[CC];
      #pragma unroll
      for(int i=0;i<CC;i++) acc[i]=p.b1[n*CC+i];
      int beg=p.row_start[n], end=p.row_start[n+1];
      for(int pp=beg;pp<end;++pp){
        int e=p.csr[pp];
        int s=p.src[e];
        float hv;
        if(l==0){
          hv = p.xT[s*BB+b];
        } else {
          float zb=(s>=FUNC_LO&&s<FUNC_HI)? z3p[e*BB+b] : p.b3[e];
          float hb=(l==1)? p.xT[s*BB+b] : p.h[e*BB+b];
          hv = hb + (zb-m)*inv*g+be;
          p.h[e*BB+b]=hv;
        }
        const float* w=&p.w1v[e*CC];
        #pragma unroll
        for(int i=0;i<CC;i++) acc[i]+=hv*w[i];
      }
      #pragma unroll
      for(int i=0;i<CC;i++) acc[i]=eluf(acc[i]);
      const float* W2=&p.w2v[fi*36];
      float z2[CC];
      #pragma unroll
      for(int j=0;j<CC;j++){
        float o=p.b2[n*CC+j];
        #pragma unroll
        for(int i=0;i<CC;i++) o+=acc[i]*W2[i*CC+j];
        z2[j]=eluf(o);
      }
      int bg2=p.row2[fi], en2=p.row2[fi+1];
      for(int pp=bg2;pp<en2;++pp){
        int k=p.csr2[pp];
        int e=p.w3c[k*CC];
        const float* w3=&p.w3v[k*CC];
        float o=p.b3[e];
        #pragma unroll
        for(int i=0;i<CC;i++) o+=z2[i]*w3[i];
        z3c[e*BB+b]=o;
        a+=o; q+=(double)o*o;
      }
    } else {
      int u=t-FB; int oi=u>>4, b=u&15;
      int e=p.csr[outBeg+oi];
      int s=p.src[e];
      float zb=(s>=FUNC_LO&&s<FUNC_HI)? z3p[e*BB+b] : p.b3[e];
      float hb=(l==1)? p.xT[s*BB+b] : p.h[e*BB+b];
      p.h[e*BB+b]=hb+(zb-m)*inv*g+be;
    }
  }
  block_add_slot(a,q,&p.part[l*NSLOT+(blockIdx.x&(NSLOT-1))]);
}

// out: apply BN_{L-1} inline to out-dst edges, sum per output node, /L.
__global__ __launch_bounds__(256) void kw_out(Params p, const float* __restrict__ z3p){
  int tid = blockIdx.x*256 + threadIdx.x, nt = gridDim.x*256;
  float m,inv;
  bn_params(p.part+(LL-1)*NSLOT, p.baseS, &m, &inv);
  float g=p.gamma[LL-1], be=p.beta[LL-1];
  for(int idx=tid;idx<BB*NN;idx+=nt){
    int b=idx/NN, n=idx-b*NN;
    float acc=0.f;
    if(n>=FUNC_HI){
      int beg=p.row_start[n], end=p.row_start[n+1];
      for(int pp=beg;pp<end;++pp){
        int e=p.csr[pp];
        int s=p.src[e];
        float zb=(s>=FUNC_LO&&s<FUNC_HI)? z3p[e*BB+b] : p.b3[e];
        acc += p.h[e*BB+b] + (zb-m)*inv*g+be;
      }
      acc *= (1.0f/(float)LL);
    }
    p.out[idx]=acc;
  }
}

extern "C" void kernel_launch(void* const* d_in, const int* in_sizes, int n_in,
                              void* d_out, int out_size, void* d_ws, size_t ws_size,
                              hipStream_t stream){
  Params p;
  p.x    =(const float*)d_in[0];
  p.src  =(const int*)  d_in[1];
  p.dst  =(const int*)  d_in[2];
  p.w1v  =(const float*)d_in[6];
  p.b1   =(const float*)d_in[7];
  p.w2v  =(const float*)d_in[10];
  p.b2   =(const float*)d_in[11];
  p.w3r  =(const int*)  d_in[12];
  p.w3c  =(const int*)  d_in[13];
  p.w3v  =(const float*)d_in[14];
  p.b3   =(const float*)d_in[15];
  p.gamma=(const float*)d_in[16];
  p.beta =(const float*)d_in[17];
  p.out  =(float*)d_out;
  p.F    = in_sizes[8]/36;
  p.Ksel = in_sizes[12]/CC;

  char* ws=(char*)d_ws; size_t off=0;
  auto alloc=[&](size_t bytes)->char*{
    char* q=ws+off; off=(off+bytes+255)&~(size_t)255; return q;
  };
  p.row_start=(int*)  alloc((NN+1)*sizeof(int));
  p.row2     =(int*)  alloc((size_t)(p.F+1)*sizeof(int));
  p.csr      =(int*)  alloc(NE*sizeof(int));
  p.csr2     =(int*)  alloc(NE*sizeof(int));
  p.xT       =(float*)alloc((size_t)NN*BB*sizeof(float));
  p.h        =(float*)alloc((size_t)NE*BB*sizeof(float));
  p.z3a      =(float*)alloc((size_t)NE*BB*sizeof(float));
  p.z3b      =(float*)alloc((size_t)NE*BB*sizeof(float));
  // zero-initialized block (single memset): counts, fill, counts2, fill2, part, baseS
  p.counts   =(int*)  alloc(NN*sizeof(int));
  p.fill     =(int*)  alloc(NN*sizeof(int));
  p.counts2  =(int*)  alloc((size_t)p.F*sizeof(int));
  p.fill2    =(int*)  alloc((size_t)p.F*sizeof(int));
  p.part     =(Slot*) alloc((size_t)LL*NSLOT*sizeof(Slot));
  p.baseS    =(Slot*) alloc((size_t)NSLOT*sizeof(Slot));
  (void)ws_size; (void)n_in; (void)out_size;

  size_t zspan = (char*)(p.baseS+NSLOT) - (char*)p.counts;
  hipMemsetAsync(p.counts, 0, zspan, stream);

  float* bufs[2] = { p.z3a, p.z3b };

  kw_P1  <<<512,256,0,stream>>>(p);
  kw_scan<<<2,  256,0,stream>>>(p);
  kw_fill<<<512,256,0,stream>>>(p);
  for(int l=0;l<LL;l++){
    kw_AB<<<768,256,0,stream>>>(p, l, bufs[(l^1)&1], bufs[l&1]);
  }
  kw_out<<<(BB*NN+255)/256,256,0,stream>>>(p, bufs[(LL-1)&1]);
}

// Round 7
// 230.374 us; speedup vs baseline: 1.3748x; 1.3748x over previous
//
#include <hip/hip_runtime.h>
#include <math.h>

#define NN 10000
#define NE 100000
#define CC 6
#define LL 6
#define BB 16
#define FUNC_LO 100
#define FUNC_HI 9900
#define EPSF 1e-5f
#define NSLOT 64

struct Slot { double s1, s2; double pad[6]; };  // 64B-padded

struct Params {
  const float *x, *w1v, *b1, *w2v, *b2, *w3v, *b3, *gamma, *beta;
  const int *src, *dst, *w3r, *w3c;
  float *out;
  int *row_start, *counts, *fill, *slot;     // dst-CSR rows; slot[e] = position of e
  int *row2, *counts2, *fill2, *csr2;        // func node -> outgoing selected-edge rows (k)
  float4 *grec;   // per dst-slot:  {w1[0..3]} {w1[4],w1[5],src(bits),b3}
  float4 *srec;   // per src-slot:  {w3[0..3]} {w3[4],w3[5],slot(bits),b3}
  float *xT, *h, *z3a, *z3b;
  Slot *part, *baseS;
  int F, Ksel;
};

__device__ __forceinline__ float eluf(float x){ return x > 0.0f ? x : expm1f(x); }

__device__ void block_add_slot(double a, double q, Slot* sl){
  __shared__ double sb1[4], sb2[4];
  #pragma unroll
  for(int off=32;off;off>>=1){ a+=__shfl_down(a,off); q+=__shfl_down(q,off); }
  int wid = threadIdx.x>>6;
  if((threadIdx.x&63)==0){ sb1[wid]=a; sb2[wid]=q; }
  __syncthreads();
  if(threadIdx.x==0){
    double A=sb1[0]+sb1[1]+sb1[2]+sb1[3];
    double Q=sb2[0]+sb2[1]+sb2[2]+sb2[3];
    if(A!=0.0) atomicAdd(&sl->s1,A);
    if(Q!=0.0) atomicAdd(&sl->s2,Q);
  }
  __syncthreads();
}

__device__ void bn_params(const Slot* part, const Slot* baseS, float* m, float* inv){
  __shared__ double s_mv[2];
  if(threadIdx.x < NSLOT){
    double a = part[threadIdx.x].s1 + baseS[threadIdx.x].s1;
    double q = part[threadIdx.x].s2 + baseS[threadIdx.x].s2;
    #pragma unroll
    for(int off=32;off;off>>=1){ a+=__shfl_down(a,off); q+=__shfl_down(q,off); }
    if(threadIdx.x==0){
      const double cnt = (double)NE*(double)BB;
      double md = a/cnt, vd = q/cnt - md*md;
      s_mv[0]=md; s_mv[1]=1.0/sqrt(vd+(double)EPSF);
    }
  }
  __syncthreads();
  *m=(float)s_mv[0]; *inv=(float)s_mv[1];
  __syncthreads();
}

// P1: transpose x -> xT; dst histogram; src-selected histogram; base BN sums
// (non-func-src edges keep z3 = b3[e] every layer -> constant contribution).
__global__ __launch_bounds__(256) void kw_P1(Params p){
  int tid = blockIdx.x*256 + threadIdx.x, nt = gridDim.x*256;
  for(int i=tid;i<NN*BB;i+=nt){ int n=i>>4, b=i&15; p.xT[i]=p.x[b*NN+n]; }
  double a=0.0,q=0.0;
  for(int e=tid;e<NE;e+=nt){
    atomicAdd(&p.counts[p.dst[e]],1);
    int s=p.src[e];
    if(!(s>=FUNC_LO && s<FUNC_HI)){ double v=(double)p.b3[e]; a+=v; q+=v*v; }
  }
  for(int k=tid;k<p.Ksel;k+=nt){
    int s=p.w3r[k*CC]/CC;
    atomicAdd(&p.counts2[s-FUNC_LO],1);
  }
  block_add_slot(a*BB, q*BB, &p.baseS[blockIdx.x&(NSLOT-1)]);
}

// Two independent single-block scans: block 0 -> dst-CSR, block 1 -> src-CSR.
__global__ __launch_bounds__(256) void kw_scan(Params p){
  __shared__ int s_scan[256];
  const int*  cin  = (blockIdx.x==0)? p.counts : p.counts2;
  int*        rout = (blockIdx.x==0)? p.row_start : p.row2;
  const int   nel  = (blockIdx.x==0)? NN : p.F;
  const int   CH   = (nel+255)/256;
  int t=threadIdx.x, base=t*CH, s=0;
  for(int k=0;k<CH;k++){ int i=base+k; if(i<nel) s+=cin[i]; }
  s_scan[t]=s; __syncthreads();
  for(int off=1;off<256;off<<=1){
    int v=(t>=off)?s_scan[t-off]:0; __syncthreads();
    s_scan[t]+=v; __syncthreads();
  }
  int run=s_scan[t]-s;
  for(int k=0;k<CH;k++){ int i=base+k; if(i<nel){ rout[i]=run; run+=cin[i]; } }
  if(t==255) rout[nel]=s_scan[255];
}

// Fill: dst-CSR -> slot[e] + gather records (streaming reads of w1v/src/b3,
// scattered 32B record store); src-CSR -> csr2.
__global__ __launch_bounds__(256) void kw_fill(Params p){
  int tid = blockIdx.x*256 + threadIdx.x, nt = gridDim.x*256;
  for(int e=tid;e<NE;e+=nt){
    int n=p.dst[e];
    int pos=p.row_start[n]+atomicAdd(&p.fill[n],1);
    p.slot[e]=pos;
    const float* w=&p.w1v[e*CC];
    p.grec[pos*2  ]=make_float4(w[0],w[1],w[2],w[3]);
    p.grec[pos*2+1]=make_float4(w[4],w[5],__int_as_float(p.src[e]),p.b3[e]);
  }
  for(int k=tid;k<p.Ksel;k+=nt){
    int fi=p.w3r[k*CC]/CC - FUNC_LO;
    int pos=p.row2[fi]+atomicAdd(&p.fill2[fi],1);
    p.csr2[pos]=k;
  }
}

// Prep: scatter records in src-CSR order {w3[6], slot(dst-CSR), b3}.
__global__ __launch_bounds__(256) void kw_prep(Params p){
  int tid = blockIdx.x*256 + threadIdx.x, nt = gridDim.x*256;
  for(int pp=tid;pp<p.Ksel;pp+=nt){
    int k=p.csr2[pp];
    int e=p.w3c[k*CC];
    const float* w=&p.w3v[k*CC];
    p.srec[pp*2  ]=make_float4(w[0],w[1],w[2],w[3]);
    p.srec[pp*2+1]=make_float4(w[4],w[5],__int_as_float(p.slot[e]),p.b3[e]);
  }
}

// AB_l (fused, slot-indexed): per func node (16-lane group, lane=batch):
//  gather loop reads grec/z3p/h as contiguous streams, applies BN_{l-1}+
//  residual in place, accumulates z1; then z2 in registers; scatter loop
//  streams srec and writes z3c at scattered slots (no read dependence).
__global__ __launch_bounds__(256) void kw_AB(Params p, int l,
    const float* __restrict__ z3p, float* __restrict__ z3c){
  int tid = blockIdx.x*256 + threadIdx.x, nt = gridDim.x*256;
  float m=0.f, inv=0.f, g=0.f, be=0.f;
  if(l>0){
    bn_params(p.part+(l-1)*NSLOT, p.baseS, &m, &inv);
    g=p.gamma[l-1]; be=p.beta[l-1];
  }
  const int FB = p.F*BB;
  const int outBeg = p.row_start[FUNC_HI];
  const int nOutE  = p.row_start[NN] - outBeg;
  const int totalA = FB + ((l>0)? nOutE*BB : 0);
  double a=0.0, q=0.0;
  for(int t=tid;t<totalA;t+=nt){
    if(t<FB){
      int fi=t>>4, b=t&15;
      int n=FUNC_LO+fi;
      float acc[CC];
      #pragma unroll
      for(int i=0;i<CC;i++) acc[i]=p.b1[n*CC+i];
      int beg=p.row_start[n], end=p.row_start[n+1];
      for(int pp=beg;pp<end;++pp){
        float4 ra=p.grec[pp*2], rb=p.grec[pp*2+1];
        int s=__float_as_int(rb.z);
        float hv;
        if(l==0){
          hv = p.xT[s*BB+b];
        } else {
          float zb=(s>=FUNC_LO&&s<FUNC_HI)? z3p[pp*BB+b] : rb.w;
          float hb=(l==1)? p.xT[s*BB+b] : p.h[pp*BB+b];
          hv = hb + (zb-m)*inv*g+be;
          p.h[pp*BB+b]=hv;
        }
        acc[0]+=hv*ra.x; acc[1]+=hv*ra.y; acc[2]+=hv*ra.z;
        acc[3]+=hv*ra.w; acc[4]+=hv*rb.x; acc[5]+=hv*rb.y;
      }
      #pragma unroll
      for(int i=0;i<CC;i++) acc[i]=eluf(acc[i]);
      const float* W2=&p.w2v[fi*36];
      float z2[CC];
      #pragma unroll
      for(int j=0;j<CC;j++){
        float o=p.b2[n*CC+j];
        #pragma unroll
        for(int i=0;i<CC;i++) o+=acc[i]*W2[i*CC+j];
        z2[j]=eluf(o);
      }
      int bg2=p.row2[fi], en2=p.row2[fi+1];
      for(int pp=bg2;pp<en2;++pp){
        float4 ra=p.srec[pp*2], rb=p.srec[pp*2+1];
        float o = rb.w + z2[0]*ra.x + z2[1]*ra.y + z2[2]*ra.z
                       + z2[3]*ra.w + z2[4]*rb.x + z2[5]*rb.y;
        int sl=__float_as_int(rb.z);
        z3c[sl*BB+b]=o;
        a+=o; q+=(double)o*o;
      }
    } else {
      int u=t-FB; int oi=u>>4, b=u&15;
      int pp=outBeg+oi;
      float4 rb=p.grec[pp*2+1];
      int s=__float_as_int(rb.z);
      float zb=(s>=FUNC_LO&&s<FUNC_HI)? z3p[pp*BB+b] : rb.w;
      float hb=(l==1)? p.xT[s*BB+b] : p.h[pp*BB+b];
      p.h[pp*BB+b]=hb+(zb-m)*inv*g+be;
    }
  }
  block_add_slot(a,q,&p.part[l*NSLOT+(blockIdx.x&(NSLOT-1))]);
}

// out: apply BN_{L-1} inline to out-dst slots, sum per output node, /L.
__global__ __launch_bounds__(256) void kw_out(Params p, const float* __restrict__ z3p){
  int tid = blockIdx.x*256 + threadIdx.x, nt = gridDim.x*256;
  float m,inv;
  bn_params(p.part+(LL-1)*NSLOT, p.baseS, &m, &inv);
  float g=p.gamma[LL-1], be=p.beta[LL-1];
  for(int idx=tid;idx<BB*NN;idx+=nt){
    int b=idx/NN, n=idx-b*NN;
    float acc=0.f;
    if(n>=FUNC_HI){
      int beg=p.row_start[n], end=p.row_start[n+1];
      for(int pp=beg;pp<end;++pp){
        float4 rb=p.grec[pp*2+1];
        int s=__float_as_int(rb.z);
        float zb=(s>=FUNC_LO&&s<FUNC_HI)? z3p[pp*BB+b] : rb.w;
        acc += p.h[pp*BB+b] + (zb-m)*inv*g+be;
      }
      acc *= (1.0f/(float)LL);
    }
    p.out[idx]=acc;
  }
}

extern "C" void kernel_launch(void* const* d_in, const int* in_sizes, int n_in,
                              void* d_out, int out_size, void* d_ws, size_t ws_size,
                              hipStream_t stream){
  Params p;
  p.x    =(const float*)d_in[0];
  p.src  =(const int*)  d_in[1];
  p.dst  =(const int*)  d_in[2];
  p.w1v  =(const float*)d_in[6];
  p.b1   =(const float*)d_in[7];
  p.w2v  =(const float*)d_in[10];
  p.b2   =(const float*)d_in[11];
  p.w3r  =(const int*)  d_in[12];
  p.w3c  =(const int*)  d_in[13];
  p.w3v  =(const float*)d_in[14];
  p.b3   =(const float*)d_in[15];
  p.gamma=(const float*)d_in[16];
  p.beta =(const float*)d_in[17];
  p.out  =(float*)d_out;
  p.F    = in_sizes[8]/36;
  p.Ksel = in_sizes[12]/CC;

  char* ws=(char*)d_ws; size_t off=0;
  auto alloc=[&](size_t bytes)->char*{
    char* q=ws+off; off=(off+bytes+255)&~(size_t)255; return q;
  };
  p.row_start=(int*)   alloc((NN+1)*sizeof(int));
  p.row2     =(int*)   alloc((size_t)(p.F+1)*sizeof(int));
  p.slot     =(int*)   alloc(NE*sizeof(int));
  p.csr2     =(int*)   alloc(NE*sizeof(int));
  p.grec     =(float4*)alloc((size_t)NE*2*sizeof(float4));
  p.srec     =(float4*)alloc((size_t)NE*2*sizeof(float4));
  p.xT       =(float*) alloc((size_t)NN*BB*sizeof(float));
  p.h        =(float*) alloc((size_t)NE*BB*sizeof(float));
  p.z3a      =(float*) alloc((size_t)NE*BB*sizeof(float));
  p.z3b      =(float*) alloc((size_t)NE*BB*sizeof(float));
  // zero-initialized block (single memset): counts, fill, counts2, fill2, part, baseS
  p.counts   =(int*)  alloc(NN*sizeof(int));
  p.fill     =(int*)  alloc(NN*sizeof(int));
  p.counts2  =(int*)  alloc((size_t)p.F*sizeof(int));
  p.fill2    =(int*)  alloc((size_t)p.F*sizeof(int));
  p.part     =(Slot*) alloc((size_t)LL*NSLOT*sizeof(Slot));
  p.baseS    =(Slot*) alloc((size_t)NSLOT*sizeof(Slot));
  (void)ws_size; (void)n_in; (void)out_size;

  size_t zspan = (char*)(p.baseS+NSLOT) - (char*)p.counts;
  hipMemsetAsync(p.counts, 0, zspan, stream);

  float* bufs[2] = { p.z3a, p.z3b };

  kw_P1  <<<512,256,0,stream>>>(p);
  kw_scan<<<2,  256,0,stream>>>(p);
  kw_fill<<<512,256,0,stream>>>(p);
  kw_prep<<<(p.Ksel+255)/256,256,0,stream>>>(p);
  for(int l=0;l<LL;l++){
    kw_AB<<<768,256,0,stream>>>(p, l, bufs[(l^1)&1], bufs[l&1]);
  }
  kw_out<<<(BB*NN+255)/256,256,0,stream>>>(p, bufs[(LL-1)&1]);
}